// Round 1
// baseline (8270.049 us; speedup 1.0000x reference)
//
#include <hip/hip_runtime.h>
#include <hip/hip_bf16.h>

// ---------------------------------------------------------------------------
// Problem constants
// ---------------------------------------------------------------------------
#define NA 5000           // atoms
#define NE 40000          // edges
#define ET 2              // edges per block in edge kernel
// DA=128, DV=96, DD=64, NL=8, L=2

// ws layout (in floats)
//  Pt (13 transposed P tensors, [c][o][8] each), then a/v/d features, then B accumulators
static const int POFF[13] = {0, 131072, 229376, 294912, 368640, 466944, 516096,
                             589824, 663552, 696320, 761856, 811008, 843776};
#define PT_TOTAL 892928
#define A_OFF   892928          // [2][NA][128]      1,280,000
#define V_OFF   2172928         // [2][NA][96][3]    2,880,000
#define D_OFF   5052928         // [2][NA][64][9]    5,760,000
#define BA_OFF  10812928        // 1,280,000
#define BV_OFF  12092928        // 2,880,000
#define BD_OFF  14972928        // 5,760,000
#define WS_FLOATS 20732928

// output layout (floats)
#define OUT_V 640000
#define OUT_D 2080000

// Pt term offsets (order = input order)
#define OFF_000 POFF[0]
#define OFF_110 POFF[1]
#define OFF_220 POFF[2]
#define OFF_011 POFF[3]
#define OFF_101 POFF[4]
#define OFF_121 POFF[5]
#define OFF_211 POFF[6]
#define OFF_111 POFF[7]
#define OFF_022 POFF[8]
#define OFF_202 POFF[9]
#define OFF_112 POFF[10]
#define OFF_222 POFF[11]
#define OFF_212 POFF[12]

// LDS float offsets for edge kernel
#define S_AJ    0        // [2][2][128]      512
#define S_VJ    512      // [2][2][96][4]    1536 (padded for b128)
#define S_DJ    2048     // [2][2][64][12]   3072 (padded)
#define S_VDOT  5120     // [2][2][96]       384
#define S_DV    5504     // [2][2][64][4]    1024
#define S_DVT   6528     // [2][2][64][4]    1024
#define S_DDOT  7552     // [2][2][64]       256
#define S_PSIA  7808     // [2][2][128]      512
#define S_PSIV  8320     // [2][2][96][3]    1152
#define S_PSID  9472     // [2][2][64][9]    2304
#define S_TOTAL 11776
// MLP scratch aliases dead gather region [0, 7808)
#define S_H1  0          // [4][256] 1024
#define S_H2  1024       // [4][256] 1024
#define S_HV  0          // [4][192][3] 2304
#define S_HV2 2304       // [4][192][3] 2304

__device__ __forceinline__ float dot4f(float4 a, float4 b) {
  return a.x*b.x + a.y*b.y + a.z*b.z + a.w*b.w;
}
__device__ __forceinline__ float lrelu(float x) { return x > 0.f ? x : 0.1f*x; }

// ---------------------------------------------------------------------------
// P transpose: src [O][8][C] -> dst [C][O][8]
// ---------------------------------------------------------------------------
__global__ __launch_bounds__(256) void transposeP_kernel(
    const float* __restrict__ src, float* __restrict__ dst, int O, int C)
{
  int idx = blockIdx.x * 256 + threadIdx.x;
  if (idx >= O * C) return;
  int o = idx / C, c = idx % C;
#pragma unroll
  for (int k = 0; k < 8; ++k)
    dst[((size_t)c * O + o) * 8 + k] = src[((size_t)o * 8 + k) * C + c];
}

// ---------------------------------------------------------------------------
// Input projection: per atom
// ---------------------------------------------------------------------------
__global__ __launch_bounds__(256) void proj_in_kernel(
    const float* __restrict__ x_a, const float* __restrict__ x_v, const float* __restrict__ x_d,
    const float* __restrict__ Wa, const float* __restrict__ Wv, const float* __restrict__ Wd,
    float* __restrict__ a_ws, float* __restrict__ v_ws, float* __restrict__ d_ws)
{
  __shared__ float xs[992];  // xa[128] xv[288] xd[576]
  const int n = blockIdx.x, t = threadIdx.x;
  for (int q = t; q < 128; q += 256) xs[q]       = x_a[(size_t)n*128 + q];
  for (int q = t; q < 288; q += 256) xs[128 + q] = x_v[(size_t)n*288 + q];
  for (int q = t; q < 576; q += 256) xs[416 + q] = x_d[(size_t)n*576 + q];
  __syncthreads();
  {
    const float* W = &Wa[(size_t)t * 128];
    float acc = 0.f;
    for (int c = 0; c < 128; c += 4) acc += dot4f(*(const float4*)&W[c], *(const float4*)&xs[c]);
    int l = t >> 7, o = t & 127;
    a_ws[((size_t)l*NA + n)*128 + o] = acc;
  }
  if (t < 192) {
    const float* W = &Wv[(size_t)t * 96];
    float a0 = 0.f, a1 = 0.f, a2 = 0.f;
    for (int c = 0; c < 96; ++c) {
      float w = W[c]; const float* x = &xs[128 + c*3];
      a0 = fmaf(w, x[0], a0); a1 = fmaf(w, x[1], a1); a2 = fmaf(w, x[2], a2);
    }
    int l = t / 96, o = t % 96;
    float* dst = &v_ws[(((size_t)l*NA + n)*96 + o)*3];
    dst[0] = a0; dst[1] = a1; dst[2] = a2;
  }
  if (t < 128) {
    const float* W = &Wd[(size_t)t * 64];
    float acc[9] = {0,0,0,0,0,0,0,0,0};
    for (int c = 0; c < 64; ++c) {
      float w = W[c]; const float* x = &xs[416 + c*9];
#pragma unroll
      for (int j = 0; j < 9; ++j) acc[j] = fmaf(w, x[j], acc[j]);
    }
    int l = t >> 6, o = t & 63;
    float* dst = &d_ws[(((size_t)l*NA + n)*64 + o)*9];
#pragma unroll
    for (int j = 0; j < 9; ++j) dst[j] = acc[j];
  }
}

// ---------------------------------------------------------------------------
// Contraction helpers.  Pt term layout: [C][O][8].  xs: LDS columns.
// acc += sum_c ( sum_k rad[et][k]*Pt[c][o][k] ) * x[et][l][c][col]
// ---------------------------------------------------------------------------
template<int O, int C, int NCH>
__device__ __forceinline__ void contract1(const float* __restrict__ Pt,
    const float* __restrict__ xs, const float (*radr)[8], int o, int ch, float (*acc)[2])
{
  constexpr int CPC = C / NCH;
  const int c0 = ch * CPC;
  const float* p = Pt + (size_t)(c0 * O + o) * 8;
#pragma unroll 2
  for (int c = c0; c < c0 + CPC; ++c, p += O*8) {
    const float4 pa = *(const float4*)p;
    const float4 pb = *(const float4*)(p + 4);
#pragma unroll
    for (int et = 0; et < 2; ++et) {
      float w = radr[et][0]*pa.x + radr[et][1]*pa.y + radr[et][2]*pa.z + radr[et][3]*pa.w
              + radr[et][4]*pb.x + radr[et][5]*pb.y + radr[et][6]*pb.z + radr[et][7]*pb.w;
#pragma unroll
      for (int l = 0; l < 2; ++l)
        acc[et][l] = fmaf(w, xs[(et*2 + l)*C + c], acc[et][l]);
    }
  }
}

template<int O, int C, int NCH>
__device__ __forceinline__ void contract3(const float* __restrict__ Pt,
    const float* __restrict__ xs, const float (*radr)[8], int o, int ch, float (*acc)[2][3])
{
  constexpr int CPC = C / NCH;
  const int c0 = ch * CPC;
  const float* p = Pt + (size_t)(c0 * O + o) * 8;
#pragma unroll 2
  for (int c = c0; c < c0 + CPC; ++c, p += O*8) {
    const float4 pa = *(const float4*)p;
    const float4 pb = *(const float4*)(p + 4);
#pragma unroll
    for (int et = 0; et < 2; ++et) {
      float w = radr[et][0]*pa.x + radr[et][1]*pa.y + radr[et][2]*pa.z + radr[et][3]*pa.w
              + radr[et][4]*pb.x + radr[et][5]*pb.y + radr[et][6]*pb.z + radr[et][7]*pb.w;
#pragma unroll
      for (int l = 0; l < 2; ++l) {
        const float4 x = *(const float4*)&xs[((et*2 + l)*C + c)*4];
        acc[et][l][0] = fmaf(w, x.x, acc[et][l][0]);
        acc[et][l][1] = fmaf(w, x.y, acc[et][l][1]);
        acc[et][l][2] = fmaf(w, x.z, acc[et][l][2]);
      }
    }
  }
}

template<int O, int C, int NCH>
__device__ __forceinline__ void contract9(const float* __restrict__ Pt,
    const float* __restrict__ xs, const float (*radr)[8], int o, int ch, float (*acc)[2][9])
{
  constexpr int CPC = C / NCH;
  const int c0 = ch * CPC;
  const float* p = Pt + (size_t)(c0 * O + o) * 8;
#pragma unroll 2
  for (int c = c0; c < c0 + CPC; ++c, p += O*8) {
    const float4 pa = *(const float4*)p;
    const float4 pb = *(const float4*)(p + 4);
#pragma unroll
    for (int et = 0; et < 2; ++et) {
      float w = radr[et][0]*pa.x + radr[et][1]*pa.y + radr[et][2]*pa.z + radr[et][3]*pa.w
              + radr[et][4]*pb.x + radr[et][5]*pb.y + radr[et][6]*pb.z + radr[et][7]*pb.w;
#pragma unroll
      for (int l = 0; l < 2; ++l) {
        const float* xr = &xs[((et*2 + l)*C + c)*12];
        const float4 x0 = *(const float4*)xr;
        const float4 x1 = *(const float4*)(xr + 4);
        const float4 x2 = *(const float4*)(xr + 8);
        acc[et][l][0] = fmaf(w, x0.x, acc[et][l][0]);
        acc[et][l][1] = fmaf(w, x0.y, acc[et][l][1]);
        acc[et][l][2] = fmaf(w, x0.z, acc[et][l][2]);
        acc[et][l][3] = fmaf(w, x0.w, acc[et][l][3]);
        acc[et][l][4] = fmaf(w, x1.x, acc[et][l][4]);
        acc[et][l][5] = fmaf(w, x1.y, acc[et][l][5]);
        acc[et][l][6] = fmaf(w, x1.z, acc[et][l][6]);
        acc[et][l][7] = fmaf(w, x1.w, acc[et][l][7]);
        acc[et][l][8] = fmaf(w, x2.x, acc[et][l][8]);
      }
    }
  }
}

// ---------------------------------------------------------------------------
// Edge kernel: 2 edges per block, 256 threads
// ---------------------------------------------------------------------------
__global__ __launch_bounds__(256) void edge_kernel(
    const int* __restrict__ g_src, const int* __restrict__ g_dst,
    const float* __restrict__ r_ij, const float* __restrict__ Pt,
    const float* __restrict__ a_ws, const float* __restrict__ v_ws, const float* __restrict__ d_ws,
    float* __restrict__ Ba, float* __restrict__ Bv, float* __restrict__ Bd,
    const float* __restrict__ Wd_a, const float* __restrict__ W1, const float* __restrict__ b1,
    const float* __restrict__ W2, const float* __restrict__ b2,
    const float* __restrict__ W3, const float* __restrict__ b3,
    const float* __restrict__ Vd, const float* __restrict__ V1,
    const float* __restrict__ V2, const float* __restrict__ V3)
{
  __shared__ float sm[S_TOTAL];
  __shared__ float s_rad[2][8];
  __shared__ float s_rh[2][3];
  __shared__ int s_src[2], s_dst[2];
  const int t = threadIdx.x;
  const int e0 = blockIdx.x * ET;

  // ---- setup: rad / rh / indices ----
  if (t < ET) {
    const int e = e0 + t;
    s_src[t] = g_src[e]; s_dst[t] = g_dst[e];
    const float rx = r_ij[e*3+0], ry = r_ij[e*3+1], rz = r_ij[e*3+2];
    const float r2 = rx*rx + ry*ry + rz*rz;
    const float r = sqrtf(r2 + 1e-12f);
#pragma unroll
    for (int k = 0; k < 8; ++k) { const float z = 7.f*r - (float)k; s_rad[t][k] = expf(-0.5f*z*z); }
    const float nn = sqrtf(49.f*r2 + 1e-12f);
    const float s = (2.f / (1.f + expf(-nn)) - 1.f) / nn;
    s_rh[t][0] = 7.f*rx*s; s_rh[t][1] = 7.f*ry*s; s_rh[t][2] = 7.f*rz*s;
  }
  __syncthreads();

  // ---- gather dst features into LDS (padded layouts) ----
  for (int q = t; q < 512; q += 256) {     // aj
    int et = q >> 8, r = q & 255, l = r >> 7, c = r & 127;
    sm[S_AJ + q] = a_ws[((size_t)l*NA + s_dst[et])*128 + c];
  }
  for (int q = t; q < 1152; q += 256) {    // vj
    int et = q / 576, r = q % 576, l = r / 288, rr = r % 288;
    sm[S_VJ + ((et*2 + l)*96 + rr/3)*4 + rr%3] = v_ws[((size_t)l*NA + s_dst[et])*288 + rr];
  }
  for (int q = t; q < 2304; q += 256) {    // dj
    int et = q / 1152, r = q % 1152, l = r / 576, rr = r % 576;
    sm[S_DJ + ((et*2 + l)*64 + rr/9)*12 + rr%9] = d_ws[((size_t)l*NA + s_dst[et])*576 + rr];
  }
  __syncthreads();

  // ---- derived columns: vdot, dv, dvT, ddot; zero psi ----
  for (int q = t; q < 384; q += 256) {
    int et = q / 192, r = q % 192, l = r / 96, c = r % 96;
    const float* v = &sm[S_VJ + ((et*2 + l)*96 + c)*4];
    sm[S_VDOT + q] = v[0]*s_rh[et][0] + v[1]*s_rh[et][1] + v[2]*s_rh[et][2];
  }
  {
    int q = t;  // exactly 256 = 2*2*64
    int et = q / 128, r = q % 128, l = r / 64, c = r % 64;
    const float* dd = &sm[S_DJ + ((et*2 + l)*64 + c)*12];
    const float rh0 = s_rh[et][0], rh1 = s_rh[et][1], rh2 = s_rh[et][2];
    const float dv0 = dd[0]*rh0 + dd[1]*rh1 + dd[2]*rh2;
    const float dv1 = dd[3]*rh0 + dd[4]*rh1 + dd[5]*rh2;
    const float dv2 = dd[6]*rh0 + dd[7]*rh1 + dd[8]*rh2;
    const float dt0 = dd[0]*rh0 + dd[3]*rh1 + dd[6]*rh2;
    const float dt1 = dd[1]*rh0 + dd[4]*rh1 + dd[7]*rh2;
    const float dt2 = dd[2]*rh0 + dd[5]*rh1 + dd[8]*rh2;
    float* pdv = &sm[S_DV  + ((et*2 + l)*64 + c)*4];
    float* pdt = &sm[S_DVT + ((et*2 + l)*64 + c)*4];
    pdv[0] = dv0; pdv[1] = dv1; pdv[2] = dv2;
    pdt[0] = dt0; pdt[1] = dt1; pdt[2] = dt2;
    sm[S_DDOT + (et*2 + l)*64 + c] = dv0*rh0 + dv1*rh1 + dv2*rh2;
  }
  for (int q = t; q < 3968; q += 256) sm[S_PSIA + q] = 0.f;
  __syncthreads();

  float radr[2][8];
#pragma unroll
  for (int et = 0; et < 2; ++et)
#pragma unroll
    for (int k = 0; k < 8; ++k) radr[et][k] = s_rad[et][k];

  // ---- psi_a: P_000 + P_110 + P_220 (O=128, 2 c-chunks) ----
  {
    const int o = t & 127, ch = t >> 7;
    float acc[2][2] = {{0.f,0.f},{0.f,0.f}};
    contract1<128,128,2>(Pt + OFF_000, &sm[S_AJ],   radr, o, ch, acc);
    contract1<128, 96,2>(Pt + OFF_110, &sm[S_VDOT], radr, o, ch, acc);
    contract1<128, 64,2>(Pt + OFF_220, &sm[S_DDOT], radr, o, ch, acc);
#pragma unroll
    for (int et = 0; et < 2; ++et)
#pragma unroll
      for (int l = 0; l < 2; ++l)
        atomicAdd(&sm[S_PSIA + (et*2 + l)*128 + o], acc[et][l]);
  }

  // ---- psi_v: P_011 + P_121 (direct), P_101 + P_211 (rh-scaled), P_111 (cross) ----
  if (t < 192) {
    const int o = t % 96, ch = t / 96;
    float accA[2][2][3] = {}, accU[2][2][3] = {};
    float accS[2][2] = {{0.f,0.f},{0.f,0.f}};
    contract3<96, 96,2>(Pt + OFF_011, &sm[S_VJ],   radr, o, ch, accA);
    contract3<96, 64,2>(Pt + OFF_121, &sm[S_DV],   radr, o, ch, accA);
    contract1<96,128,2>(Pt + OFF_101, &sm[S_AJ],   radr, o, ch, accS);
    contract1<96, 96,2>(Pt + OFF_211, &sm[S_VDOT], radr, o, ch, accS);
    contract3<96, 96,2>(Pt + OFF_111, &sm[S_VJ],   radr, o, ch, accU);
#pragma unroll
    for (int et = 0; et < 2; ++et) {
      const float rh0 = s_rh[et][0], rh1 = s_rh[et][1], rh2 = s_rh[et][2];
#pragma unroll
      for (int l = 0; l < 2; ++l) {
        const float* u = accU[et][l];
        const float cx = rh1*u[2] - rh2*u[1];
        const float cy = rh2*u[0] - rh0*u[2];
        const float cz = rh0*u[1] - rh1*u[0];
        const float s = accS[et][l];
        float* base = &sm[S_PSIV + ((et*2 + l)*96 + o)*3];
        atomicAdd(base + 0, accA[et][l][0] + rh0*s + cx);
        atomicAdd(base + 1, accA[et][l][1] + rh1*s + cy);
        atomicAdd(base + 2, accA[et][l][2] + rh2*s + cz);
      }
    }
  }

  // ---- psi_d pass A: P_022 (O=64, 4 chunks, 9 cols) ----
  {
    const int o = t & 63, ch = t >> 6;
    float accD[2][2][9] = {};
    contract9<64,64,4>(Pt + OFF_022, &sm[S_DJ], radr, o, ch, accD);
#pragma unroll
    for (int et = 0; et < 2; ++et)
#pragma unroll
      for (int l = 0; l < 2; ++l) {
        float* base = &sm[S_PSID + ((et*2 + l)*64 + o)*9];
#pragma unroll
        for (int j = 0; j < 9; ++j) atomicAdd(base + j, accD[et][l][j]);
      }
  }
  // ---- psi_d pass B: P_202, P_112, P_222, P_212 ----
  {
    const int o = t & 63, ch = t >> 6;
    float accS[2][2] = {{0.f,0.f},{0.f,0.f}};
    float accU[2][2][3] = {}, accT[2][2][3] = {}, accW[2][2][3] = {};
    contract1<64,128,4>(Pt + OFF_202, &sm[S_AJ],  radr, o, ch, accS);
    contract3<64, 96,4>(Pt + OFF_112, &sm[S_VJ],  radr, o, ch, accU);
    contract3<64, 64,4>(Pt + OFF_222, &sm[S_DVT], radr, o, ch, accT);
    contract3<64, 96,4>(Pt + OFF_212, &sm[S_VJ],  radr, o, ch, accW);
#pragma unroll
    for (int et = 0; et < 2; ++et) {
      const float rh[3] = { s_rh[et][0], s_rh[et][1], s_rh[et][2] };
#pragma unroll
      for (int l = 0; l < 2; ++l) {
        const float* w = accW[et][l];
        const float cr[3] = { rh[1]*w[2] - rh[2]*w[1],
                              rh[2]*w[0] - rh[0]*w[2],
                              rh[0]*w[1] - rh[1]*w[0] };
        float* base = &sm[S_PSID + ((et*2 + l)*64 + o)*9];
#pragma unroll
        for (int i = 0; i < 3; ++i)
#pragma unroll
          for (int j = 0; j < 3; ++j) {
            const float val = rh[i]*rh[j]*accS[et][l]
                            + rh[i]*(accU[et][l][j] + accT[et][l][j])
                            + rh[j]*cr[i];
            atomicAdd(base + i*3 + j, val);
          }
      }
    }
  }
  __syncthreads();

  // ================= scalar MLP (h1,h2 alias dead gather LDS) ================
  {
    const int p = t;
    const float* Wrow = &W1[(size_t)p * 128];
    float acc[4] = {0.f,0.f,0.f,0.f};
    for (int c = 0; c < 128; c += 4) {
      const float4 w4 = *(const float4*)&Wrow[c];
#pragma unroll
      for (int cb = 0; cb < 4; ++cb)
        acc[cb] += dot4f(w4, *(const float4*)&sm[S_PSIA + cb*128 + c]);
    }
    const float bb = b1[p];
#pragma unroll
    for (int cb = 0; cb < 4; ++cb) sm[S_H1 + cb*256 + p] = lrelu(acc[cb] + bb);
  }
  __syncthreads();
  {
    const int p = t;
    const float* Wrow = &W2[(size_t)p * 256];
    float acc[4] = {0.f,0.f,0.f,0.f};
    for (int c = 0; c < 256; c += 4) {
      const float4 w4 = *(const float4*)&Wrow[c];
#pragma unroll
      for (int cb = 0; cb < 4; ++cb)
        acc[cb] += dot4f(w4, *(const float4*)&sm[S_H1 + cb*256 + c]);
    }
    const float bb = b2[p];
#pragma unroll
    for (int cb = 0; cb < 4; ++cb) sm[S_H2 + cb*256 + p] = lrelu(acc[cb] + bb);
  }
  __syncthreads();
  {
    const int o = t & 127, cb0 = t >> 7;   // combos cb0 and cb0+2
    const float* Wdr = &Wd_a[(size_t)o * 128];
    float acc0 = b3[o], acc1 = acc0;
    for (int c = 0; c < 128; c += 4) {
      const float4 w4 = *(const float4*)&Wdr[c];
      acc0 += dot4f(w4, *(const float4*)&sm[S_PSIA + cb0*128 + c]);
      acc1 += dot4f(w4, *(const float4*)&sm[S_PSIA + (cb0+2)*128 + c]);
    }
    const float* W3r = &W3[(size_t)o * 256];
    for (int c = 0; c < 256; c += 4) {
      const float4 w4 = *(const float4*)&W3r[c];
      acc0 += dot4f(w4, *(const float4*)&sm[S_H2 + cb0*256 + c]);
      acc1 += dot4f(w4, *(const float4*)&sm[S_H2 + (cb0+2)*256 + c]);
    }
    acc0 += sm[S_PSIA + cb0*128 + o];
    acc1 += sm[S_PSIA + (cb0+2)*128 + o];
    __syncthreads();
    sm[S_PSIA + cb0*128 + o] = acc0;
    sm[S_PSIA + (cb0+2)*128 + o] = acc1;
  }
  __syncthreads();

  // ================= vector MLP =================
  {
    float res[3][3]; int ps[3], cbs[3];
#pragma unroll
    for (int u = 0; u < 3; ++u) {
      const int unit = t + 256*u;
      const int p = unit % 192, cb = unit / 192;
      ps[u] = p; cbs[u] = cb;
      const float* Vr = &V1[(size_t)p * 96];
      float y0 = 0.f, y1 = 0.f, y2 = 0.f;
      for (int c = 0; c < 96; ++c) {
        const float w = Vr[c];
        const float* x = &sm[S_PSIV + (cb*96 + c)*3];
        y0 = fmaf(w, x[0], y0); y1 = fmaf(w, x[1], y1); y2 = fmaf(w, x[2], y2);
      }
      const float nn = sqrtf(y0*y0 + y1*y1 + y2*y2 + 1e-12f);
      const float s = (2.f / (1.f + expf(-nn)) - 1.f) / nn;
      res[u][0] = y0*s; res[u][1] = y1*s; res[u][2] = y2*s;
    }
#pragma unroll
    for (int u = 0; u < 3; ++u) {
      float* d = &sm[S_HV + (cbs[u]*192 + ps[u])*3];
      d[0] = res[u][0]; d[1] = res[u][1]; d[2] = res[u][2];
    }
  }
  __syncthreads();
  {
    float res[3][3]; int ps[3], cbs[3];
#pragma unroll
    for (int u = 0; u < 3; ++u) {
      const int unit = t + 256*u;
      const int p = unit % 192, cb = unit / 192;
      ps[u] = p; cbs[u] = cb;
      const float* Vr = &V2[(size_t)p * 192];
      float y0 = 0.f, y1 = 0.f, y2 = 0.f;
      for (int c = 0; c < 192; ++c) {
        const float w = Vr[c];
        const float* x = &sm[S_HV + (cb*192 + c)*3];
        y0 = fmaf(w, x[0], y0); y1 = fmaf(w, x[1], y1); y2 = fmaf(w, x[2], y2);
      }
      const float nn = sqrtf(y0*y0 + y1*y1 + y2*y2 + 1e-12f);
      const float s = (2.f / (1.f + expf(-nn)) - 1.f) / nn;
      res[u][0] = y0*s; res[u][1] = y1*s; res[u][2] = y2*s;
    }
#pragma unroll
    for (int u = 0; u < 3; ++u) {
      float* d = &sm[S_HV2 + (cbs[u]*192 + ps[u])*3];
      d[0] = res[u][0]; d[1] = res[u][1]; d[2] = res[u][2];
    }
  }
  __syncthreads();
  {
    float r0[3], r1[3];
    const int o0 = t % 96, cb0_ = t / 96;
    {
      const float* Vdr = &Vd[(size_t)o0 * 96];
      float a0 = 0.f, a1 = 0.f, a2 = 0.f;
      for (int c = 0; c < 96; ++c) {
        const float w = Vdr[c]; const float* x = &sm[S_PSIV + (cb0_*96 + c)*3];
        a0 = fmaf(w, x[0], a0); a1 = fmaf(w, x[1], a1); a2 = fmaf(w, x[2], a2);
      }
      const float* V3r = &V3[(size_t)o0 * 192];
      for (int q = 0; q < 192; ++q) {
        const float w = V3r[q]; const float* x = &sm[S_HV2 + (cb0_*192 + q)*3];
        a0 = fmaf(w, x[0], a0); a1 = fmaf(w, x[1], a1); a2 = fmaf(w, x[2], a2);
      }
      const float* x = &sm[S_PSIV + (cb0_*96 + o0)*3];
      r0[0] = x[0] + a0; r0[1] = x[1] + a1; r0[2] = x[2] + a2;
    }
    const int o1 = (t + 256) % 96, cb1_ = (t + 256) / 96;
    if (t < 128) {
      const float* Vdr = &Vd[(size_t)o1 * 96];
      float a0 = 0.f, a1 = 0.f, a2 = 0.f;
      for (int c = 0; c < 96; ++c) {
        const float w = Vdr[c]; const float* x = &sm[S_PSIV + (cb1_*96 + c)*3];
        a0 = fmaf(w, x[0], a0); a1 = fmaf(w, x[1], a1); a2 = fmaf(w, x[2], a2);
      }
      const float* V3r = &V3[(size_t)o1 * 192];
      for (int q = 0; q < 192; ++q) {
        const float w = V3r[q]; const float* x = &sm[S_HV2 + (cb1_*192 + q)*3];
        a0 = fmaf(w, x[0], a0); a1 = fmaf(w, x[1], a1); a2 = fmaf(w, x[2], a2);
      }
      const float* x = &sm[S_PSIV + (cb1_*96 + o1)*3];
      r1[0] = x[0] + a0; r1[1] = x[1] + a1; r1[2] = x[2] + a2;
    }
    __syncthreads();
    {
      float* d = &sm[S_PSIV + (cb0_*96 + o0)*3];
      d[0] = r0[0]; d[1] = r0[1]; d[2] = r0[2];
    }
    if (t < 128) {
      float* d = &sm[S_PSIV + (cb1_*96 + o1)*3];
      d[0] = r1[0]; d[1] = r1[1]; d[2] = r1[2];
    }
  }
  __syncthreads();

  // ================= scatter-add to src atoms =================
  for (int q = t; q < 512; q += 256) {
    int et = q >> 8, r = q & 255, l = r >> 7, o = r & 127;
    unsafeAtomicAdd(&Ba[((size_t)l*NA + s_src[et])*128 + o], sm[S_PSIA + q]);
  }
  for (int q = t; q < 1152; q += 256) {
    int et = q / 576, r = q % 576, l = r / 288, rr = r % 288;
    unsafeAtomicAdd(&Bv[((size_t)l*NA + s_src[et])*288 + rr], sm[S_PSIV + q]);
  }
  for (int q = t; q < 2304; q += 256) {
    int et = q / 1152, r = q % 1152, l = r / 576, rr = r % 576;
    unsafeAtomicAdd(&Bd[((size_t)l*NA + s_src[et])*576 + rr], sm[S_PSID + q]);
  }
}

// ---------------------------------------------------------------------------
// Output projection: per atom
// ---------------------------------------------------------------------------
__global__ __launch_bounds__(256) void proj_out_kernel(
    const float* __restrict__ Ba, const float* __restrict__ Bv, const float* __restrict__ Bd,
    const float* __restrict__ Wa, const float* __restrict__ Wv, const float* __restrict__ Wd,
    float* __restrict__ out)
{
  __shared__ float bs[256 + 576 + 1152];
  const int n = blockIdx.x, t = threadIdx.x;
  for (int q = t; q < 256; q += 256) {
    int l = q >> 7, c = q & 127;
    bs[q] = Ba[((size_t)l*NA + n)*128 + c];
  }
  for (int q = t; q < 576; q += 256) {
    int l = q / 288, rr = q % 288;
    bs[256 + q] = Bv[((size_t)l*NA + n)*288 + rr];
  }
  for (int q = t; q < 1152; q += 256) {
    int l = q / 576, rr = q % 576;
    bs[832 + q] = Bd[((size_t)l*NA + n)*576 + rr];
  }
  __syncthreads();
  if (t < 128) {
    const float* W = &Wa[(size_t)t * 256];
    float acc = 0.f;
    for (int c = 0; c < 256; c += 4) acc += dot4f(*(const float4*)&W[c], *(const float4*)&bs[c]);
    out[(size_t)n*128 + t] = acc;
  }
  if (t < 96) {
    const float* W = &Wv[(size_t)t * 192];
    float a0 = 0.f, a1 = 0.f, a2 = 0.f;
    for (int c = 0; c < 192; ++c) {
      const float w = W[c]; const float* x = &bs[256 + c*3];
      a0 = fmaf(w, x[0], a0); a1 = fmaf(w, x[1], a1); a2 = fmaf(w, x[2], a2);
    }
    float* d = &out[OUT_V + ((size_t)n*96 + t)*3];
    d[0] = a0; d[1] = a1; d[2] = a2;
  }
  if (t < 64) {
    const float* W = &Wd[(size_t)t * 128];
    float acc[9] = {0,0,0,0,0,0,0,0,0};
    for (int c = 0; c < 128; ++c) {
      const float w = W[c]; const float* x = &bs[832 + c*9];
#pragma unroll
      for (int j = 0; j < 9; ++j) acc[j] = fmaf(w, x[j], acc[j]);
    }
    float* d = &out[OUT_D + ((size_t)n*64 + t)*9];
#pragma unroll
    for (int j = 0; j < 9; ++j) d[j] = acc[j];
  }
}

// ---------------------------------------------------------------------------
// Host entry
// ---------------------------------------------------------------------------
extern "C" void kernel_launch(void* const* d_in, const int* in_sizes, int n_in,
                              void* d_out, int out_size, void* d_ws, size_t ws_size,
                              hipStream_t stream) {
  (void)in_sizes; (void)n_in; (void)out_size; (void)ws_size;
  const int*   src  = (const int*)d_in[0];
  const int*   dst  = (const int*)d_in[1];
  const float* r_ij = (const float*)d_in[2];
  const float* x_a  = (const float*)d_in[3];
  const float* x_v  = (const float*)d_in[4];
  const float* x_d  = (const float*)d_in[5];
  const float* P[13];
  for (int i = 0; i < 13; ++i) P[i] = (const float*)d_in[6 + i];
  const float* W_in_a  = (const float*)d_in[19];
  const float* W_in_v  = (const float*)d_in[20];
  const float* W_in_d  = (const float*)d_in[21];
  const float* W_out_a = (const float*)d_in[22];
  const float* W_out_v = (const float*)d_in[23];
  const float* W_out_d = (const float*)d_in[24];
  const float* Wd_a = (const float*)d_in[25];
  const float* W1   = (const float*)d_in[26];
  const float* b1   = (const float*)d_in[27];
  const float* W2   = (const float*)d_in[28];
  const float* b2   = (const float*)d_in[29];
  const float* W3   = (const float*)d_in[30];
  const float* b3   = (const float*)d_in[31];
  const float* Vd   = (const float*)d_in[32];
  const float* V1   = (const float*)d_in[33];
  const float* V2   = (const float*)d_in[34];
  const float* V3   = (const float*)d_in[35];

  float* ws = (float*)d_ws;
  float* Pt = ws;

  // 1) transpose all 13 P tensors to [c][o][8]
  static const int Od[13] = {128,128,128, 96, 96, 96, 96, 96, 64, 64, 64, 64, 64};
  static const int Cd[13] = {128, 96, 64, 96,128, 64, 96, 96, 64,128, 96, 64, 96};
  for (int i = 0; i < 13; ++i) {
    const int total = Od[i] * Cd[i];
    transposeP_kernel<<<(total + 255) / 256, 256, 0, stream>>>(P[i], Pt + POFF[i], Od[i], Cd[i]);
  }

  // 2) zero the scatter accumulators
  hipMemsetAsync(ws + BA_OFF, 0, (size_t)(WS_FLOATS - BA_OFF) * sizeof(float), stream);

  // 3) input projections
  proj_in_kernel<<<NA, 256, 0, stream>>>(x_a, x_v, x_d, W_in_a, W_in_v, W_in_d,
                                         ws + A_OFF, ws + V_OFF, ws + D_OFF);

  // 4) edge messages + MLPs + scatter
  edge_kernel<<<NE / ET, 256, 0, stream>>>(src, dst, r_ij, Pt,
                                           ws + A_OFF, ws + V_OFF, ws + D_OFF,
                                           ws + BA_OFF, ws + BV_OFF, ws + BD_OFF,
                                           Wd_a, W1, b1, W2, b2, W3, b3,
                                           Vd, V1, V2, V3);

  // 5) output projections
  proj_out_kernel<<<NA, 256, 0, stream>>>(ws + BA_OFF, ws + BV_OFF, ws + BD_OFF,
                                          W_out_a, W_out_v, W_out_d, (float*)d_out);
}

// Round 2
// 5697.119 us; speedup vs baseline: 1.4516x; 1.4516x over previous
//
#include <hip/hip_runtime.h>
#include <hip/hip_bf16.h>

// ---------------------------------------------------------------------------
// Problem constants
// ---------------------------------------------------------------------------
#define NA 5000           // atoms
#define NE 40000          // edges
// DA=128, DV=96, DD=64, NL=8, L=2

// ---------------------------------------------------------------------------
// Workspace layout (float indices)
// ---------------------------------------------------------------------------
static const int POFF[13] = {0, 131072, 229376, 294912, 368640, 466944, 516096,
                             589824, 663552, 696320, 761856, 811008, 843776};
#define PT_TOTAL 892928
#define A_OFF    892928          // a  [2][NA][128]
#define V_OFF    2172928         // v  [2][NA][288]
#define D_OFF    5052928         // d  [2][NA][576]
#define BA_OFF   10812928
#define BV_OFF   12092928
#define BD_OFF   14972928
#define PHI_OFF  20732928        // [NE][12] rad0..7, rh0..2, pad
#define PSIA_OFF 21212928        // [NE sorted][2][128]
#define PSIV_OFF 31452928        // [NE sorted][2][288]
#define INT_OFF  54492928        // int region below (as int index from here)
// int region (indices into (int*)(ws + INT_OFF))
#define ICNT  0                  // [NA]
#define IOFF  5120               // [NA+1]
#define ICUR  10240              // [NA]
#define IEIDX 15360              // [NE]
#define ISRC  55360              // [NE] src gathered in sorted order

// output layout (floats)
#define OUT_V 640000
#define OUT_D 2080000

#define OFF_000 POFF[0]
#define OFF_110 POFF[1]
#define OFF_220 POFF[2]
#define OFF_011 POFF[3]
#define OFF_101 POFF[4]
#define OFF_121 POFF[5]
#define OFF_211 POFF[6]
#define OFF_111 POFF[7]
#define OFF_022 POFF[8]
#define OFF_202 POFF[9]
#define OFF_112 POFF[10]
#define OFF_222 POFF[11]
#define OFF_212 POFF[12]

// msg kernel LDS layout (floats)
#define S_XA   0       // [2][128]
#define S_XV   256     // [2][288]  (c*3+i)
#define S_XD   832     // [2][576]  (c*9+3i+j)
#define S_PHI  1984    // [8][12]
#define S_PSIA 2080    // [8][2][128]
#define S_PSIV 4128    // [8][2][96*3]
#define S_PSID 8736    // [8][2][64*9]
#define S_TOT  17952   // 71808 B -> 2 blocks/CU

__device__ __forceinline__ float dot4f(float4 a, float4 b) {
  return a.x*b.x + a.y*b.y + a.z*b.z + a.w*b.w;
}
__device__ __forceinline__ float lrelu(float x) { return x > 0.f ? x : 0.1f*x; }

// ---------------------------------------------------------------------------
// P transpose: src [O][8][C] -> dst [C][O][8]
// ---------------------------------------------------------------------------
__global__ __launch_bounds__(256) void transposeP_kernel(
    const float* __restrict__ src, float* __restrict__ dst, int O, int C)
{
  int idx = blockIdx.x * 256 + threadIdx.x;
  if (idx >= O * C) return;
  int o = idx / C, c = idx % C;
#pragma unroll
  for (int k = 0; k < 8; ++k)
    dst[((size_t)c * O + o) * 8 + k] = src[((size_t)o * 8 + k) * C + c];
}

// ---------------------------------------------------------------------------
// Sorting: counting sort of edges by dst
// ---------------------------------------------------------------------------
__global__ __launch_bounds__(256) void hist_kernel(const int* __restrict__ dst, int* __restrict__ cnt) {
  int e = blockIdx.x * 256 + threadIdx.x;
  if (e < NE) atomicAdd(&cnt[dst[e]], 1);
}

__global__ __launch_bounds__(256) void scan_kernel(const int* __restrict__ cnt, int* __restrict__ off) {
  __shared__ int part[256];
  const int t = threadIdx.x;
  int loc[20]; int s = 0;
#pragma unroll
  for (int i = 0; i < 20; ++i) {
    int idx = t * 20 + i;
    int v = (idx < NA) ? cnt[idx] : 0;
    loc[i] = v; s += v;
  }
  part[t] = s; __syncthreads();
  for (int ofs = 1; ofs < 256; ofs <<= 1) {
    int v = (t >= ofs) ? part[t - ofs] : 0;
    __syncthreads();
    part[t] += v;
    __syncthreads();
  }
  int run = part[t] - s;   // exclusive prefix
#pragma unroll
  for (int i = 0; i < 20; ++i) {
    int idx = t * 20 + i;
    if (idx < NA) off[idx] = run;
    run += loc[i];
  }
  if (t == 255) off[NA] = run;
}

__global__ __launch_bounds__(256) void sort_scatter_kernel(
    const int* __restrict__ dst, const int* __restrict__ off,
    int* __restrict__ cur, int* __restrict__ eidx)
{
  int e = blockIdx.x * 256 + threadIdx.x;
  if (e >= NE) return;
  int d = dst[e];
  int pos = off[d] + atomicAdd(&cur[d], 1);
  eidx[pos] = e;
}

// per sorted edge: rad[8], rh[3]; gather src
__global__ __launch_bounds__(256) void phi_kernel(
    const int* __restrict__ eidx, const int* __restrict__ src,
    const float* __restrict__ r_ij, float* __restrict__ phi, int* __restrict__ srcs)
{
  int p = blockIdx.x * 256 + threadIdx.x;
  if (p >= NE) return;
  int e = eidx[p];
  const float rx = r_ij[e*3+0], ry = r_ij[e*3+1], rz = r_ij[e*3+2];
  const float r2 = rx*rx + ry*ry + rz*rz;
  const float r = sqrtf(r2 + 1e-12f);
#pragma unroll
  for (int k = 0; k < 8; ++k) {
    const float z = 7.f*r - (float)k;
    phi[(size_t)p*12 + k] = expf(-0.5f*z*z);
  }
  const float nn = sqrtf(49.f*r2 + 1e-12f);
  const float sc = (2.f / (1.f + expf(-nn)) - 1.f) / nn;
  phi[(size_t)p*12 + 8]  = 7.f*rx*sc;
  phi[(size_t)p*12 + 9]  = 7.f*ry*sc;
  phi[(size_t)p*12 + 10] = 7.f*rz*sc;
  phi[(size_t)p*12 + 11] = 0.f;
  srcs[p] = src[e];
}

// ---------------------------------------------------------------------------
// Input projection (per atom)
// ---------------------------------------------------------------------------
__global__ __launch_bounds__(256) void proj_in_kernel(
    const float* __restrict__ x_a, const float* __restrict__ x_v, const float* __restrict__ x_d,
    const float* __restrict__ Wa, const float* __restrict__ Wv, const float* __restrict__ Wd,
    float* __restrict__ a_ws, float* __restrict__ v_ws, float* __restrict__ d_ws)
{
  __shared__ float xs[992];  // xa[128] xv[288] xd[576]
  const int n = blockIdx.x, t = threadIdx.x;
  for (int q = t; q < 128; q += 256) xs[q]       = x_a[(size_t)n*128 + q];
  for (int q = t; q < 288; q += 256) xs[128 + q] = x_v[(size_t)n*288 + q];
  for (int q = t; q < 576; q += 256) xs[416 + q] = x_d[(size_t)n*576 + q];
  __syncthreads();
  {
    const float* W = &Wa[(size_t)t * 128];
    float acc = 0.f;
    for (int c = 0; c < 128; c += 4) acc += dot4f(*(const float4*)&W[c], *(const float4*)&xs[c]);
    int l = t >> 7, o = t & 127;
    a_ws[((size_t)l*NA + n)*128 + o] = acc;
  }
  if (t < 192) {
    const float* W = &Wv[(size_t)t * 96];
    float a0 = 0.f, a1 = 0.f, a2 = 0.f;
    for (int c = 0; c < 96; ++c) {
      float w = W[c]; const float* x = &xs[128 + c*3];
      a0 = fmaf(w, x[0], a0); a1 = fmaf(w, x[1], a1); a2 = fmaf(w, x[2], a2);
    }
    int l = t / 96, o = t % 96;
    float* dstp = &v_ws[(((size_t)l*NA + n)*96 + o)*3];
    dstp[0] = a0; dstp[1] = a1; dstp[2] = a2;
  }
  if (t < 128) {
    const float* W = &Wd[(size_t)t * 64];
    float acc[9] = {0,0,0,0,0,0,0,0,0};
    for (int c = 0; c < 64; ++c) {
      float w = W[c]; const float* x = &xs[416 + c*9];
#pragma unroll
      for (int j = 0; j < 9; ++j) acc[j] = fmaf(w, x[j], acc[j]);
    }
    int l = t >> 6, o = t & 63;
    float* dstp = &d_ws[(((size_t)l*NA + n)*64 + o)*9];
#pragma unroll
    for (int j = 0; j < 9; ++j) dstp[j] = acc[j];
  }
}

// ---------------------------------------------------------------------------
// Z compute: z[k][m] = sum_c Pt[c][o][k] * xl[c*NMU+m]   (Pt layout [C][O][8])
// ---------------------------------------------------------------------------
#define ZBODY                                                     \
    {                                                             \
      const float4 p0 = *(const float4*)p;                        \
      const float4 p1 = *(const float4*)(p + 4);                  \
      _Pragma("unroll")                                           \
      for (int m = 0; m < NMU; ++m) {                             \
        const float xv = xl[c * NMU + m];                         \
        z[0][m] = fmaf(p0.x, xv, z[0][m]);                        \
        z[1][m] = fmaf(p0.y, xv, z[1][m]);                        \
        z[2][m] = fmaf(p0.z, xv, z[2][m]);                        \
        z[3][m] = fmaf(p0.w, xv, z[3][m]);                        \
        z[4][m] = fmaf(p1.x, xv, z[4][m]);                        \
        z[5][m] = fmaf(p1.y, xv, z[5][m]);                        \
        z[6][m] = fmaf(p1.z, xv, z[6][m]);                        \
        z[7][m] = fmaf(p1.w, xv, z[7][m]);                        \
      }                                                           \
    }

template<int O, int C, int NMU>
__device__ __forceinline__ void zcompute(const float* __restrict__ Pt,
    const float* __restrict__ xl, int o, float z[8][NMU])
{
#pragma unroll
  for (int k = 0; k < 8; ++k)
#pragma unroll
    for (int m = 0; m < NMU; ++m) z[k][m] = 0.f;
  const float* p = Pt + o * 8;
  if constexpr (NMU <= 3) {
#pragma unroll 4
    for (int c = 0; c < C; ++c, p += O * 8) ZBODY
  } else {
#pragma unroll 2
    for (int c = 0; c < C; ++c, p += O * 8) ZBODY
  }
}

template<int NMU>
__device__ __forceinline__ float kdot(const float z[8][NMU], int m, const float* rr) {
  float s = z[0][m] * rr[0];
#pragma unroll
  for (int k = 1; k < 8; ++k) s = fmaf(z[k][m], rr[k], s);
  return s;
}

#define LOADPH(e)                                                  \
  const float* ph = &sm[S_PHI + (e)*12];                           \
  float rr[8] = {ph[0],ph[1],ph[2],ph[3],ph[4],ph[5],ph[6],ph[7]}; \
  const float q0 = ph[8], q1 = ph[9], q2 = ph[10];

// ---------------------------------------------------------------------------
// Message kernel: one block per dst atom; chunks of <=8 edges
// ---------------------------------------------------------------------------
__global__ __launch_bounds__(256, 2) void msg_kernel(
    const int* __restrict__ off, const float* __restrict__ phi, const int* __restrict__ srcs,
    const float* __restrict__ Pt,
    const float* __restrict__ a_ws, const float* __restrict__ v_ws, const float* __restrict__ d_ws,
    float* __restrict__ psiA, float* __restrict__ psiV, float* __restrict__ Bd)
{
  __shared__ float sm[S_TOT];
  __shared__ int s_src[8];
  const int n = blockIdx.x, t = threadIdx.x;
  const int e0 = off[n], e1 = off[n + 1];
  if (e0 == e1) return;

  // load this atom's features (both l)
  for (int q = t; q < 256; q += 256)
    sm[S_XA + q] = a_ws[((size_t)(q >> 7)*NA + n)*128 + (q & 127)];
  for (int q = t; q < 576; q += 256)
    sm[S_XV + q] = v_ws[((size_t)(q / 288)*NA + n)*288 + (q % 288)];
  for (int q = t; q < 1152; q += 256)
    sm[S_XD + q] = d_ws[((size_t)(q / 576)*NA + n)*576 + (q % 576)];

  for (int cb = e0; cb < e1; cb += 8) {
    const int E = min(8, e1 - cb);
    // zero psi + load edge meta
    for (int q = t; q < 15872; q += 256) sm[S_PSIA + q] = 0.f;
    if (t < E * 12) sm[S_PHI + t] = phi[(size_t)(cb + t / 12) * 12 + t % 12];
    if (t < E) s_src[t] = srcs[cb + t];
    __syncthreads();

    // ============ psi_a terms (O=128, all 256 threads) ============
    {
      const int o = t & 127, l = t >> 7;
      { // 000: a input, 1 col
        float z[8][1];
        zcompute<128, 128, 1>(Pt + OFF_000, &sm[S_XA + l*128], o, z);
        for (int e = 0; e < E; ++e) {
          LOADPH(e); (void)q0; (void)q1; (void)q2;
          sm[S_PSIA + (e*2 + l)*128 + o] += kdot<1>(z, 0, rr);
        }
      }
      { // 110: v input, 3 cols
        float z[8][3];
        zcompute<128, 96, 3>(Pt + OFF_110, &sm[S_XV + l*288], o, z);
        for (int e = 0; e < E; ++e) {
          LOADPH(e);
          float s0 = kdot<3>(z,0,rr), s1 = kdot<3>(z,1,rr), s2 = kdot<3>(z,2,rr);
          sm[S_PSIA + (e*2 + l)*128 + o] += q0*s0 + q1*s1 + q2*s2;
        }
      }
      { // 220: d input, 9 cols
        float z[8][9];
        zcompute<128, 64, 9>(Pt + OFF_220, &sm[S_XD + l*576], o, z);
        for (int e = 0; e < E; ++e) {
          LOADPH(e);
          float s[9];
#pragma unroll
          for (int m = 0; m < 9; ++m) s[m] = kdot<9>(z, m, rr);
          float acc = q0*(q0*s[0] + q1*s[1] + q2*s[2])
                    + q1*(q0*s[3] + q1*s[4] + q2*s[5])
                    + q2*(q0*s[6] + q1*s[7] + q2*s[8]);
          sm[S_PSIA + (e*2 + l)*128 + o] += acc;
        }
      }
    }

    // ============ psi_v terms (O=96, threads t<192) ============
    if (t < 192) {
      const int o = t % 96, l = t / 96;
      { // 011: v, direct
        float z[8][3];
        zcompute<96, 96, 3>(Pt + OFF_011, &sm[S_XV + l*288], o, z);
        for (int e = 0; e < E; ++e) {
          LOADPH(e); (void)q0; (void)q1; (void)q2;
          float* pv = &sm[S_PSIV + ((e*2 + l)*96 + o)*3];
          pv[0] += kdot<3>(z,0,rr); pv[1] += kdot<3>(z,1,rr); pv[2] += kdot<3>(z,2,rr);
        }
      }
      { // 101: a, * rh_i
        float z[8][1];
        zcompute<96, 128, 1>(Pt + OFF_101, &sm[S_XA + l*128], o, z);
        for (int e = 0; e < E; ++e) {
          LOADPH(e);
          float s0 = kdot<1>(z, 0, rr);
          float* pv = &sm[S_PSIV + ((e*2 + l)*96 + o)*3];
          pv[0] += q0*s0; pv[1] += q1*s0; pv[2] += q2*s0;
        }
      }
      { // 121: d, sum_j rh_j s[3i+j]
        float z[8][9];
        zcompute<96, 64, 9>(Pt + OFF_121, &sm[S_XD + l*576], o, z);
        for (int e = 0; e < E; ++e) {
          LOADPH(e);
          float s[9];
#pragma unroll
          for (int m = 0; m < 9; ++m) s[m] = kdot<9>(z, m, rr);
          float* pv = &sm[S_PSIV + ((e*2 + l)*96 + o)*3];
          pv[0] += q0*s[0] + q1*s[1] + q2*s[2];
          pv[1] += q0*s[3] + q1*s[4] + q2*s[5];
          pv[2] += q0*s[6] + q1*s[7] + q2*s[8];
        }
      }
      { // 211: v, rh_i * (sum_j rh_j s[j])
        float z[8][3];
        zcompute<96, 96, 3>(Pt + OFF_211, &sm[S_XV + l*288], o, z);
        for (int e = 0; e < E; ++e) {
          LOADPH(e);
          float tt = q0*kdot<3>(z,0,rr) + q1*kdot<3>(z,1,rr) + q2*kdot<3>(z,2,rr);
          float* pv = &sm[S_PSIV + ((e*2 + l)*96 + o)*3];
          pv[0] += q0*tt; pv[1] += q1*tt; pv[2] += q2*tt;
        }
      }
      { // 111: v, rh x s
        float z[8][3];
        zcompute<96, 96, 3>(Pt + OFF_111, &sm[S_XV + l*288], o, z);
        for (int e = 0; e < E; ++e) {
          LOADPH(e);
          float s0 = kdot<3>(z,0,rr), s1 = kdot<3>(z,1,rr), s2 = kdot<3>(z,2,rr);
          float* pv = &sm[S_PSIV + ((e*2 + l)*96 + o)*3];
          pv[0] += q1*s2 - q2*s1;
          pv[1] += q2*s0 - q0*s2;
          pv[2] += q0*s1 - q1*s0;
        }
      }
    }

    // ============ psi_d terms (O=64, threads t<128) ============
    if (t < 128) {
      const int o = t & 63, l = t >> 6;
      { // 022: d, direct 9
        float z[8][9];
        zcompute<64, 64, 9>(Pt + OFF_022, &sm[S_XD + l*576], o, z);
        for (int e = 0; e < E; ++e) {
          LOADPH(e); (void)q0; (void)q1; (void)q2;
          float* pd = &sm[S_PSID + ((e*2 + l)*64 + o)*9];
#pragma unroll
          for (int m = 0; m < 9; ++m) pd[m] += kdot<9>(z, m, rr);
        }
      }
      { // 202: a, rh_i rh_j s
        float z[8][1];
        zcompute<64, 128, 1>(Pt + OFF_202, &sm[S_XA + l*128], o, z);
        for (int e = 0; e < E; ++e) {
          LOADPH(e);
          float s0 = kdot<1>(z, 0, rr);
          float* pd = &sm[S_PSID + ((e*2 + l)*64 + o)*9];
          pd[0] += q0*q0*s0; pd[1] += q0*q1*s0; pd[2] += q0*q2*s0;
          pd[3] += q1*q0*s0; pd[4] += q1*q1*s0; pd[5] += q1*q2*s0;
          pd[6] += q2*q0*s0; pd[7] += q2*q1*s0; pd[8] += q2*q2*s0;
        }
      }
      { // 112: v, rh_i * s[j]
        float z[8][3];
        zcompute<64, 96, 3>(Pt + OFF_112, &sm[S_XV + l*288], o, z);
        for (int e = 0; e < E; ++e) {
          LOADPH(e);
          float s0 = kdot<3>(z,0,rr), s1 = kdot<3>(z,1,rr), s2 = kdot<3>(z,2,rr);
          float* pd = &sm[S_PSID + ((e*2 + l)*64 + o)*9];
          pd[0] += q0*s0; pd[1] += q0*s1; pd[2] += q0*s2;
          pd[3] += q1*s0; pd[4] += q1*s1; pd[5] += q1*s2;
          pd[6] += q2*s0; pd[7] += q2*s1; pd[8] += q2*s2;
        }
      }
      { // 222: d, u[j]=sum_k rh_k s[3k+j]; pd[ij] += rh_i u[j]
        float z[8][9];
        zcompute<64, 64, 9>(Pt + OFF_222, &sm[S_XD + l*576], o, z);
        for (int e = 0; e < E; ++e) {
          LOADPH(e);
          float s[9];
#pragma unroll
          for (int m = 0; m < 9; ++m) s[m] = kdot<9>(z, m, rr);
          const float u0 = q0*s[0] + q1*s[3] + q2*s[6];
          const float u1 = q0*s[1] + q1*s[4] + q2*s[7];
          const float u2 = q0*s[2] + q1*s[5] + q2*s[8];
          float* pd = &sm[S_PSID + ((e*2 + l)*64 + o)*9];
          pd[0] += q0*u0; pd[1] += q0*u1; pd[2] += q0*u2;
          pd[3] += q1*u0; pd[4] += q1*u1; pd[5] += q1*u2;
          pd[6] += q2*u0; pd[7] += q2*u1; pd[8] += q2*u2;
        }
      }
      { // 212: v, c=rh x s; pd[ij] += c_i rh_j
        float z[8][3];
        zcompute<64, 96, 3>(Pt + OFF_212, &sm[S_XV + l*288], o, z);
        for (int e = 0; e < E; ++e) {
          LOADPH(e);
          float s0 = kdot<3>(z,0,rr), s1 = kdot<3>(z,1,rr), s2 = kdot<3>(z,2,rr);
          const float c0 = q1*s2 - q2*s1;
          const float c1 = q2*s0 - q0*s2;
          const float c2 = q0*s1 - q1*s0;
          float* pd = &sm[S_PSID + ((e*2 + l)*64 + o)*9];
          pd[0] += c0*q0; pd[1] += c0*q1; pd[2] += c0*q2;
          pd[3] += c1*q0; pd[4] += c1*q1; pd[5] += c1*q2;
          pd[6] += c2*q0; pd[7] += c2*q1; pd[8] += c2*q2;
        }
      }
    }
    __syncthreads();

    // store psi_a / psi_v (sorted slots); scatter psi_d to Bd
    for (int q = t; q < E * 256; q += 256)
      psiA[(size_t)(cb + (q >> 8)) * 256 + (q & 255)] = sm[S_PSIA + q];
    for (int q = t; q < E * 576; q += 256)
      psiV[(size_t)(cb + q / 576) * 576 + (q % 576)] = sm[S_PSIV + q];
    for (int q = t; q < E * 1152; q += 256) {
      const int el = q / 1152, r = q % 1152, l = r / 576;
      unsafeAtomicAdd(&Bd[((size_t)l*NA + s_src[el])*576 + (r % 576)], sm[S_PSID + q]);
    }
    __syncthreads();
  }
}

// ---------------------------------------------------------------------------
// Scalar MLP + scatter (48 combos/block; combo = sorted_slot*2 + l)
// ---------------------------------------------------------------------------
__global__ __launch_bounds__(256, 2) void mlp_a_kernel(
    const float* __restrict__ psiA, const int* __restrict__ srcs,
    const float* __restrict__ Wd_a,
    const float* __restrict__ W1, const float* __restrict__ b1,
    const float* __restrict__ W2, const float* __restrict__ b2,
    const float* __restrict__ W3, const float* __restrict__ b3,
    float* __restrict__ Ba)
{
  __shared__ float PA[48*128];
  __shared__ float H1[48*256];
  __shared__ float H2[48*256];
  const int t = threadIdx.x;
  const int cbase = blockIdx.x * 48;
  const int ncl = min(48, 2*NE - cbase);

  for (int q = t; q < 48*128; q += 256) {
    int j = q >> 7;
    PA[q] = (j < ncl) ? psiA[(size_t)(cbase + j)*128 + (q & 127)] : 0.f;
  }
  __syncthreads();
  { // h1 = lrelu(W1 psi + b1), 256 rows
    const float* Wr = &W1[(size_t)t * 128];
    const float bb = b1[t];
    for (int c0 = 0; c0 < 48; c0 += 8) {
      float acc[8] = {0,0,0,0,0,0,0,0};
      for (int c = 0; c < 128; c += 4) {
        const float4 w4 = *(const float4*)&Wr[c];
#pragma unroll
        for (int j = 0; j < 8; ++j)
          acc[j] += dot4f(w4, *(const float4*)&PA[(c0 + j)*128 + c]);
      }
#pragma unroll
      for (int j = 0; j < 8; ++j) H1[(c0 + j)*256 + t] = lrelu(acc[j] + bb);
    }
  }
  __syncthreads();
  { // h2 = lrelu(W2 h1 + b2)
    const float* Wr = &W2[(size_t)t * 256];
    const float bb = b2[t];
    for (int c0 = 0; c0 < 48; c0 += 8) {
      float acc[8] = {0,0,0,0,0,0,0,0};
      for (int c = 0; c < 256; c += 4) {
        const float4 w4 = *(const float4*)&Wr[c];
#pragma unroll
        for (int j = 0; j < 8; ++j)
          acc[j] += dot4f(w4, *(const float4*)&H1[(c0 + j)*256 + c]);
      }
#pragma unroll
      for (int j = 0; j < 8; ++j) H2[(c0 + j)*256 + t] = lrelu(acc[j] + bb);
    }
  }
  __syncthreads();
  { // out = psi + Wd psi + W3 h2 + b3; scatter to Ba
    const int o = t & 127, g = t >> 7;
    const float* Wdr = &Wd_a[(size_t)o * 128];
    const float* W3r = &W3[(size_t)o * 256];
    const float bb = b3[o];
    for (int c0 = g*24; c0 < g*24 + 24; c0 += 8) {
      float acc[8] = {0,0,0,0,0,0,0,0};
      for (int c = 0; c < 128; c += 4) {
        const float4 w4 = *(const float4*)&Wdr[c];
#pragma unroll
        for (int j = 0; j < 8; ++j)
          acc[j] += dot4f(w4, *(const float4*)&PA[(c0 + j)*128 + c]);
      }
      for (int c = 0; c < 256; c += 4) {
        const float4 w4 = *(const float4*)&W3r[c];
#pragma unroll
        for (int j = 0; j < 8; ++j)
          acc[j] += dot4f(w4, *(const float4*)&H2[(c0 + j)*256 + c]);
      }
#pragma unroll
      for (int j = 0; j < 8; ++j) {
        if (c0 + j < ncl) {
          const int cid = cbase + c0 + j;
          const int p = cid >> 1, l = cid & 1;
          const float val = acc[j] + bb + PA[(c0 + j)*128 + o];
          unsafeAtomicAdd(&Ba[((size_t)l*NA + srcs[p])*128 + o], val);
        }
      }
    }
  }
}

// ---------------------------------------------------------------------------
// Vector MLP + scatter (24 combos/block)
// LDS layouts: PV [cb][i][96], HV/HV2 [cb][i][192]
// ---------------------------------------------------------------------------
__global__ __launch_bounds__(256, 2) void mlp_v_kernel(
    const float* __restrict__ psiV, const int* __restrict__ srcs,
    const float* __restrict__ Vd, const float* __restrict__ V1,
    const float* __restrict__ V2, const float* __restrict__ V3,
    float* __restrict__ Bv)
{
  __shared__ float PV[24*288];
  __shared__ float HV[24*576];
  __shared__ float HV2[24*576];
  const int t = threadIdx.x;
  const int cbase = blockIdx.x * 24;
  const int ncl = min(24, 2*NE - cbase);

  for (int q = t; q < 24*288; q += 256) {
    const int j = q / 288, r = q % 288;
    const float val = (j < ncl) ? psiV[(size_t)(cbase + j)*288 + r] : 0.f;
    PV[j*288 + (r % 3)*96 + r/3] = val;
  }
  __syncthreads();
  if (t < 192) { // hv = tsig(V1 psi), 192 rows
    const float* Vr = &V1[(size_t)t * 96];
    for (int c0 = 0; c0 < 24; c0 += 4) {
      float acc[4][3] = {};
      for (int c = 0; c < 96; c += 4) {
        const float4 w4 = *(const float4*)&Vr[c];
#pragma unroll
        for (int j = 0; j < 4; ++j)
#pragma unroll
          for (int i = 0; i < 3; ++i)
            acc[j][i] += dot4f(w4, *(const float4*)&PV[(c0 + j)*288 + i*96 + c]);
      }
#pragma unroll
      for (int j = 0; j < 4; ++j) {
        const float nn = sqrtf(acc[j][0]*acc[j][0] + acc[j][1]*acc[j][1] + acc[j][2]*acc[j][2] + 1e-12f);
        const float sc = (2.f / (1.f + expf(-nn)) - 1.f) / nn;
#pragma unroll
        for (int i = 0; i < 3; ++i) HV[(c0 + j)*576 + i*192 + t] = acc[j][i]*sc;
      }
    }
  }
  __syncthreads();
  if (t < 192) { // hv2 = tsig(V2 hv)
    const float* Vr = &V2[(size_t)t * 192];
    for (int c0 = 0; c0 < 24; c0 += 4) {
      float acc[4][3] = {};
      for (int c = 0; c < 192; c += 4) {
        const float4 w4 = *(const float4*)&Vr[c];
#pragma unroll
        for (int j = 0; j < 4; ++j)
#pragma unroll
          for (int i = 0; i < 3; ++i)
            acc[j][i] += dot4f(w4, *(const float4*)&HV[(c0 + j)*576 + i*192 + c]);
      }
#pragma unroll
      for (int j = 0; j < 4; ++j) {
        const float nn = sqrtf(acc[j][0]*acc[j][0] + acc[j][1]*acc[j][1] + acc[j][2]*acc[j][2] + 1e-12f);
        const float sc = (2.f / (1.f + expf(-nn)) - 1.f) / nn;
#pragma unroll
        for (int i = 0; i < 3; ++i) HV2[(c0 + j)*576 + i*192 + t] = acc[j][i]*sc;
      }
    }
  }
  __syncthreads();
  if (t < 192) { // out = psi + Vd psi + V3 hv2; scatter to Bv
    const int o = t % 96, g = t / 96;
    const float* Vdr = &Vd[(size_t)o * 96];
    const float* V3r = &V3[(size_t)o * 192];
    for (int c0 = g*12; c0 < g*12 + 12; c0 += 4) {
      float acc[4][3] = {};
      for (int c = 0; c < 96; c += 4) {
        const float4 w4 = *(const float4*)&Vdr[c];
#pragma unroll
        for (int j = 0; j < 4; ++j)
#pragma unroll
          for (int i = 0; i < 3; ++i)
            acc[j][i] += dot4f(w4, *(const float4*)&PV[(c0 + j)*288 + i*96 + c]);
      }
      for (int c = 0; c < 192; c += 4) {
        const float4 w4 = *(const float4*)&V3r[c];
#pragma unroll
        for (int j = 0; j < 4; ++j)
#pragma unroll
          for (int i = 0; i < 3; ++i)
            acc[j][i] += dot4f(w4, *(const float4*)&HV2[(c0 + j)*576 + i*192 + c]);
      }
#pragma unroll
      for (int j = 0; j < 4; ++j) {
        if (c0 + j < ncl) {
          const int cid = cbase + c0 + j;
          const int p = cid >> 1, l = cid & 1;
          const int s = srcs[p];
#pragma unroll
          for (int i = 0; i < 3; ++i) {
            const float val = acc[j][i] + PV[(c0 + j)*288 + i*96 + o];
            unsafeAtomicAdd(&Bv[((size_t)l*NA + s)*288 + o*3 + i], val);
          }
        }
      }
    }
  }
}

// ---------------------------------------------------------------------------
// Output projection (per atom)
// ---------------------------------------------------------------------------
__global__ __launch_bounds__(256) void proj_out_kernel(
    const float* __restrict__ Ba, const float* __restrict__ Bv, const float* __restrict__ Bd,
    const float* __restrict__ Wa, const float* __restrict__ Wv, const float* __restrict__ Wd,
    float* __restrict__ out)
{
  __shared__ float bs[256 + 576 + 1152];
  const int n = blockIdx.x, t = threadIdx.x;
  for (int q = t; q < 256; q += 256)
    bs[q] = Ba[((size_t)(q >> 7)*NA + n)*128 + (q & 127)];
  for (int q = t; q < 576; q += 256)
    bs[256 + q] = Bv[((size_t)(q / 288)*NA + n)*288 + (q % 288)];
  for (int q = t; q < 1152; q += 256)
    bs[832 + q] = Bd[((size_t)(q / 576)*NA + n)*576 + (q % 576)];
  __syncthreads();
  if (t < 128) {
    const float* W = &Wa[(size_t)t * 256];
    float acc = 0.f;
    for (int c = 0; c < 256; c += 4) acc += dot4f(*(const float4*)&W[c], *(const float4*)&bs[c]);
    out[(size_t)n*128 + t] = acc;
  }
  if (t < 96) {
    const float* W = &Wv[(size_t)t * 192];
    float a0 = 0.f, a1 = 0.f, a2 = 0.f;
    for (int c = 0; c < 192; ++c) {
      const float w = W[c]; const float* x = &bs[256 + c*3];
      a0 = fmaf(w, x[0], a0); a1 = fmaf(w, x[1], a1); a2 = fmaf(w, x[2], a2);
    }
    float* d = &out[OUT_V + ((size_t)n*96 + t)*3];
    d[0] = a0; d[1] = a1; d[2] = a2;
  }
  if (t < 64) {
    const float* W = &Wd[(size_t)t * 128];
    float acc[9] = {0,0,0,0,0,0,0,0,0};
    for (int c = 0; c < 128; ++c) {
      const float w = W[c]; const float* x = &bs[832 + c*9];
#pragma unroll
      for (int j = 0; j < 9; ++j) acc[j] = fmaf(w, x[j], acc[j]);
    }
    float* d = &out[OUT_D + ((size_t)n*64 + t)*9];
#pragma unroll
    for (int j = 0; j < 9; ++j) d[j] = acc[j];
  }
}

// ---------------------------------------------------------------------------
// Host entry
// ---------------------------------------------------------------------------
extern "C" void kernel_launch(void* const* d_in, const int* in_sizes, int n_in,
                              void* d_out, int out_size, void* d_ws, size_t ws_size,
                              hipStream_t stream) {
  (void)in_sizes; (void)n_in; (void)out_size; (void)ws_size;
  const int*   src  = (const int*)d_in[0];
  const int*   dst  = (const int*)d_in[1];
  const float* r_ij = (const float*)d_in[2];
  const float* x_a  = (const float*)d_in[3];
  const float* x_v  = (const float*)d_in[4];
  const float* x_d  = (const float*)d_in[5];
  const float* P[13];
  for (int i = 0; i < 13; ++i) P[i] = (const float*)d_in[6 + i];
  const float* W_in_a  = (const float*)d_in[19];
  const float* W_in_v  = (const float*)d_in[20];
  const float* W_in_d  = (const float*)d_in[21];
  const float* W_out_a = (const float*)d_in[22];
  const float* W_out_v = (const float*)d_in[23];
  const float* W_out_d = (const float*)d_in[24];
  const float* Wd_a = (const float*)d_in[25];
  const float* W1   = (const float*)d_in[26];
  const float* b1   = (const float*)d_in[27];
  const float* W2   = (const float*)d_in[28];
  const float* b2   = (const float*)d_in[29];
  const float* W3   = (const float*)d_in[30];
  const float* b3   = (const float*)d_in[31];
  const float* Vd   = (const float*)d_in[32];
  const float* V1   = (const float*)d_in[33];
  const float* V2   = (const float*)d_in[34];
  const float* V3   = (const float*)d_in[35];

  float* ws = (float*)d_ws;
  float* Pt = ws;
  int*   ib = (int*)(ws + INT_OFF);

  // 1) transpose P tensors to [C][O][8]
  static const int Od[13] = {128,128,128, 96, 96, 96, 96, 96, 64, 64, 64, 64, 64};
  static const int Cd[13] = {128, 96, 64, 96,128, 64, 96, 96, 64,128, 96, 64, 96};
  for (int i = 0; i < 13; ++i) {
    const int total = Od[i] * Cd[i];
    transposeP_kernel<<<(total + 255) / 256, 256, 0, stream>>>(P[i], Pt + POFF[i], Od[i], Cd[i]);
  }

  // 2) zero scatter accumulators + sort counters
  hipMemsetAsync(ws + BA_OFF, 0, (size_t)(PHI_OFF - BA_OFF) * sizeof(float), stream);
  hipMemsetAsync(ib, 0, (size_t)(ICUR + NA) * sizeof(int), stream);

  // 3) counting sort by dst + per-edge radial/vector encodings
  const int egrid = (NE + 255) / 256;
  hist_kernel<<<egrid, 256, 0, stream>>>(dst, ib + ICNT);
  scan_kernel<<<1, 256, 0, stream>>>(ib + ICNT, ib + IOFF);
  sort_scatter_kernel<<<egrid, 256, 0, stream>>>(dst, ib + IOFF, ib + ICUR, ib + IEIDX);
  phi_kernel<<<egrid, 256, 0, stream>>>(ib + IEIDX, src, r_ij, ws + PHI_OFF, ib + ISRC);

  // 4) input projections
  proj_in_kernel<<<NA, 256, 0, stream>>>(x_a, x_v, x_d, W_in_a, W_in_v, W_in_d,
                                         ws + A_OFF, ws + V_OFF, ws + D_OFF);

  // 5) messages (per dst atom), psi_d scattered directly
  msg_kernel<<<NA, 256, 0, stream>>>(ib + IOFF, ws + PHI_OFF, ib + ISRC, Pt,
                                     ws + A_OFF, ws + V_OFF, ws + D_OFF,
                                     ws + PSIA_OFF, ws + PSIV_OFF, ws + BD_OFF);

  // 6) edge MLPs + scatter
  mlp_a_kernel<<<(2*NE + 47) / 48, 256, 0, stream>>>(ws + PSIA_OFF, ib + ISRC,
                                                     Wd_a, W1, b1, W2, b2, W3, b3,
                                                     ws + BA_OFF);
  mlp_v_kernel<<<(2*NE + 23) / 24, 256, 0, stream>>>(ws + PSIV_OFF, ib + ISRC,
                                                     Vd, V1, V2, V3,
                                                     ws + BV_OFF);

  // 7) output projections
  proj_out_kernel<<<NA, 256, 0, stream>>>(ws + BA_OFF, ws + BV_OFF, ws + BD_OFF,
                                          W_out_a, W_out_v, W_out_d, (float*)d_out);
}